// Round 5
// baseline (151.899 us; speedup 1.0000x reference)
//
#include <hip/hip_runtime.h>

#define L_FFT 4096
#define NCH 512

typedef __attribute__((ext_vector_type(8))) short bf16x8;
typedef __attribute__((ext_vector_type(4))) float f32x4;

__device__ __forceinline__ void split_bf16(float x, unsigned short& h, unsigned short& l) {
  unsigned u = __float_as_uint(x);
  h = (unsigned short)(u >> 16);                    // truncate -> hi
  float fh = __uint_as_float(u & 0xffff0000u);
  float lo = x - fh;                                // exact residual
  l = (unsigned short)(__float_as_uint(lo) >> 16);  // truncate -> lo
}

// ---------------------------------------------------------------------------
// k0a: phase tables ctab/stab[4096] = cos/sin(2*pi*ph/4096)
// ---------------------------------------------------------------------------
__global__ __launch_bounds__(256) void k0a_phase(float* __restrict__ ctab,
                                                 float* __restrict__ stab) {
  int i = blockIdx.x * 256 + threadIdx.x;  // 0..4095
  float s, c;
  sincosf(6.2831853071795864769f / 4096.f * (float)i, &s, &c);
  ctab[i] = c;
  stab[i] = s;
}

// ---------------------------------------------------------------------------
// k0b: expand phase tables into MFMA-fragment-swizzled bf16 hi/lo tables.
// T1f (forward B): idx = ((chunk*2+wn)*4+ni)*512 + lane*8 + i
//   kcol = wn*64+ni*16+(lane&15), l = chunk*32+(lane>>4)*8+i
// T2f (inverse B): idx = (lt16*4+kc2)*512 + lane*8 + i
//   l = lt16*16+(lane&15), k = kc2*32+(lane>>4)*8+i
// ---------------------------------------------------------------------------
__global__ __launch_bounds__(256) void k0b_expand(const int* __restrict__ index,
                                                  const float* __restrict__ ctab,
                                                  const float* __restrict__ stab,
                                                  unsigned short* __restrict__ T1fh,
                                                  unsigned short* __restrict__ T1fl,
                                                  unsigned short* __restrict__ T2fh,
                                                  unsigned short* __restrict__ T2fl) {
  int idx = blockIdx.x * 256 + threadIdx.x;  // 0..524287
  int i = idx & 7, lane = (idx >> 3) & 63;
  int m16 = lane & 15, kg = lane >> 4;
  {
    int ni = (idx >> 9) & 3, wn = (idx >> 11) & 1, chunk = idx >> 12;
    int kcol = wn * 64 + ni * 16 + m16;
    int l = chunk * 32 + kg * 8 + i;
    int f = index[kcol & 63];
    int ph = (l * f) & 4095;
    float v = (kcol < 64) ? ctab[ph] : -stab[ph];
    unsigned short h, lo;
    split_bf16(v, h, lo);
    T1fh[idx] = h;
    T1fl[idx] = lo;
  }
  {
    int kc2 = (idx >> 9) & 3, lt16 = idx >> 11;
    int l = lt16 * 16 + m16;
    int k = kc2 * 32 + kg * 8 + i;
    int ph = (l * (k & 63)) & 4095;
    float v = (k < 64) ? ctab[ph] : stab[ph];
    unsigned short h, lo;
    split_bf16(v, h, lo);
    T2fh[idx] = h;
    T2fl[idx] = lo;
  }
}

// ---------------------------------------------------------------------------
// k1: forward GEMM, zero LDS, register-pipelined.
// part[p][c][k] = sum_l X[c,l]*T1[k,l]
// Block 64c x 128k (4 waves; wave 32c x 64k as 2x4 of 16x16x32), chunk=32 l.
// Per chunk: issue B (L2-hot) just-in-time, prefetch NEXT chunk's A gather
// (HBM latency) into the other register buffer, then split/pack + MFMA.
// ---------------------------------------------------------------------------
__global__ __launch_bounds__(256, 4) void k1_forward(const float* __restrict__ q,
                                                     const unsigned short* __restrict__ T1fh,
                                                     const unsigned short* __restrict__ T1fl,
                                                     float* __restrict__ part,
                                                     int kspan) {
  int ctile = blockIdx.x;  // 0..127
  int p = blockIdx.y;
  int b = ctile >> 3, ch0 = (ctile & 7) * 64;
  int t = threadIdx.x, wave = t >> 6, lane = t & 63;
  int wm = wave >> 1, wn = wave & 1, m16 = lane & 15, kg = lane >> 4;
  int nchunk = kspan >> 5;
  int chunk0 = (p * kspan) >> 5;

  float xf[2][2][8];
  // prologue: A gather for chunk0
#pragma unroll
  for (int mi = 0; mi < 2; ++mi) {
    int c = ch0 + wm * 32 + mi * 16 + m16;
    const float* qp = q + ((size_t)b * L_FFT + (size_t)chunk0 * 32 + kg * 8) * NCH + c;
#pragma unroll
    for (int i = 0; i < 8; ++i) xf[0][mi][i] = qp[(size_t)i * NCH];
  }

  f32x4 acc[2][4] = {};

  for (int cc = 0; cc < nchunk; ++cc) {
    int cur = cc & 1;
    int chunk = chunk0 + cc;
    // ---- B loads for current chunk (L2-hot, short latency) ----
    bf16x8 bh[4], bl[4];
#pragma unroll
    for (int ni = 0; ni < 4; ++ni) {
      size_t off = ((size_t)((chunk * 2 + wn) * 4 + ni) << 9) + lane * 8;
      bh[ni] = *(const bf16x8*)(T1fh + off);
      bl[ni] = *(const bf16x8*)(T1fl + off);
    }
    // ---- prefetch next chunk's A gather (HBM latency hidden under compute) ----
    if (cc + 1 < nchunk) {
#pragma unroll
      for (int mi = 0; mi < 2; ++mi) {
        int c = ch0 + wm * 32 + mi * 16 + m16;
        const float* qp = q + ((size_t)b * L_FFT + (size_t)(chunk + 1) * 32 + kg * 8) * NCH + c;
#pragma unroll
        for (int i = 0; i < 8; ++i) xf[cur ^ 1][mi][i] = qp[(size_t)i * NCH];
      }
    }
    // ---- split/pack + MFMA on current buffer ----
#pragma unroll
    for (int mi = 0; mi < 2; ++mi) {
      union { bf16x8 v; unsigned w[4]; } ah, al;
#pragma unroll
      for (int j = 0; j < 4; ++j) {
        float x0 = xf[cur][mi][2 * j], x1 = xf[cur][mi][2 * j + 1];
        unsigned u0 = __float_as_uint(x0), u1 = __float_as_uint(x1);
        ah.w[j] = (u0 >> 16) | (u1 & 0xffff0000u);
        float l0 = x0 - __uint_as_float(u0 & 0xffff0000u);
        float l1 = x1 - __uint_as_float(u1 & 0xffff0000u);
        al.w[j] = (__float_as_uint(l0) >> 16) | (__float_as_uint(l1) & 0xffff0000u);
      }
#pragma unroll
      for (int ni = 0; ni < 4; ++ni) {
        acc[mi][ni] = __builtin_amdgcn_mfma_f32_16x16x32_bf16(ah.v, bh[ni], acc[mi][ni], 0, 0, 0);
        acc[mi][ni] = __builtin_amdgcn_mfma_f32_16x16x32_bf16(ah.v, bl[ni], acc[mi][ni], 0, 0, 0);
        acc[mi][ni] = __builtin_amdgcn_mfma_f32_16x16x32_bf16(al.v, bh[ni], acc[mi][ni], 0, 0, 0);
      }
    }
  }

  int base_c = ctile * 64 + wm * 32;
  float* dst = part + (size_t)p * 1048576;
#pragma unroll
  for (int mi = 0; mi < 2; ++mi)
#pragma unroll
    for (int ni = 0; ni < 4; ++ni) {
      int row0 = base_c + mi * 16 + kg * 4;
      int col = wn * 64 + ni * 16 + m16;
#pragma unroll
      for (int r = 0; r < 4; ++r)
        __builtin_nontemporal_store(acc[mi][ni][r],
                                    &dst[(size_t)(row0 + r) * 128 + col]);
    }
}

// k1b: reduce split-K partials -> g [8192][128] f32
__global__ __launch_bounds__(256) void k1b_reduce(const float* __restrict__ part,
                                                  float* __restrict__ g, int np) {
  int idx = blockIdx.x * 256 + threadIdx.x;
  float s = 0.f;
  for (int p = 0; p < np; ++p) s += part[(size_t)p * 1048576 + idx];
  g[idx] = s;
}

// ---------------------------------------------------------------------------
// k2: mode mix + irfft coefficient prep -> Afh/Afl bf16, k3-fragment-swizzled.
// (round-3 version: grid (16,8,16), g-slice in LDS, w streamed through L3)
// afidx(c,k) = (((c>>4)*4+(k>>5))*64 + ((k>>3)&3)*16 + (c&15))*8 + (k&7)
// ---------------------------------------------------------------------------
__global__ __launch_bounds__(256) void k2_mix(const float* __restrict__ g,
                                              const float* __restrict__ wre,
                                              const float* __restrict__ wim,
                                              unsigned short* __restrict__ Afh,
                                              unsigned short* __restrict__ Afl) {
  int oq = blockIdx.x;  // 16
  int h = blockIdx.y;   // 8
  int b = blockIdx.z;   // 16
  __shared__ float gre[64][64], gim[64][64];
  int t = threadIdx.x;
  int bh = b * 8 + h;
#pragma unroll
  for (int j = 0; j < 16; ++j) {
    int idx = j * 256 + t, ir = idx >> 6, mr = idx & 63;
    const float* row = &g[((size_t)bh * 64 + ir) * 128];
    gre[ir][mr] = row[mr];
    gim[ir][mr] = row[64 + mr];
  }
  __syncthreads();
  int o = oq * 4 + (t >> 6), m = t & 63;
  float are = 0.f, aim = 0.f;
  for (int i = 0; i < 64; ++i) {
    float gr = gre[i][m], gi = gim[i][m];
    int wofs = ((h * 64 + i) * 64 + o) * 64 + m;
    float wr = wre[wofs], wi = wim[wofs];
    are = fmaf(gr, wr, are);
    are = fmaf(-gi, wi, are);
    aim = fmaf(gr, wi, aim);
    aim = fmaf(gi, wr, aim);
  }
  const float invL = 1.0f / (float)L_FFT;
  float outre = are * ((m == 0) ? invL : 2.0f * invL);
  float outim = (m == 0) ? 0.0f : (-2.0f * invL) * aim;
  int c = bh * 64 + o;
  unsigned short h16, l16;
  {
    int k = m;
    int afidx = (((c >> 4) * 4 + (k >> 5)) * 64 + ((k >> 3) & 3) * 16 + (c & 15)) * 8 + (k & 7);
    split_bf16(outre, h16, l16);
    Afh[afidx] = h16;
    Afl[afidx] = l16;
  }
  {
    int k = 64 + m;
    int afidx = (((c >> 4) * 4 + (k >> 5)) * 64 + ((k >> 3) & 3) * 16 + (c & 15)) * 8 + (k & 7);
    split_bf16(outim, h16, l16);
    Afh[afidx] = h16;
    Afl[afidx] = l16;
  }
}

// ---------------------------------------------------------------------------
// k3: inverse GEMM, zero LDS, all operands fragment-swizzled & coalesced.
// y[c][l] = sum_k A[c][k] * T2[l][k]; block 128c x 128l, K=128 in 4 chunks.
// ---------------------------------------------------------------------------
__global__ __launch_bounds__(256) void k3_inverse(const unsigned short* __restrict__ Afh,
                                                  const unsigned short* __restrict__ Afl,
                                                  const unsigned short* __restrict__ T2fh,
                                                  const unsigned short* __restrict__ T2fl,
                                                  float* __restrict__ y) {
  int ltile = blockIdx.x;   // 0..31
  int c0 = blockIdx.y * 128;
  int t = threadIdx.x, wave = t >> 6, lane = t & 63;
  int wm = wave >> 1, wn = wave & 1, m16 = lane & 15, kg = lane >> 4;

  f32x4 acc[4][4] = {};

#pragma unroll
  for (int kc2 = 0; kc2 < 4; ++kc2) {
    bf16x8 bh[4], bl[4];
#pragma unroll
    for (int ni = 0; ni < 4; ++ni) {
      size_t off = ((size_t)((ltile * 8 + wn * 4 + ni) * 4 + kc2) << 9) + lane * 8;
      bh[ni] = *(const bf16x8*)(T2fh + off);
      bl[ni] = *(const bf16x8*)(T2fl + off);
    }
#pragma unroll
    for (int mi = 0; mi < 4; ++mi) {
      int c16 = (c0 >> 4) + wm * 4 + mi;
      size_t off = ((size_t)(c16 * 4 + kc2) << 9) + lane * 8;
      bf16x8 ah = *(const bf16x8*)(Afh + off);
      bf16x8 al = *(const bf16x8*)(Afl + off);
#pragma unroll
      for (int ni = 0; ni < 4; ++ni) {
        acc[mi][ni] = __builtin_amdgcn_mfma_f32_16x16x32_bf16(ah, bh[ni], acc[mi][ni], 0, 0, 0);
        acc[mi][ni] = __builtin_amdgcn_mfma_f32_16x16x32_bf16(ah, bl[ni], acc[mi][ni], 0, 0, 0);
        acc[mi][ni] = __builtin_amdgcn_mfma_f32_16x16x32_bf16(al, bh[ni], acc[mi][ni], 0, 0, 0);
      }
    }
  }

#pragma unroll
  for (int mi = 0; mi < 4; ++mi)
#pragma unroll
    for (int ni = 0; ni < 4; ++ni) {
      int row0 = c0 + wm * 64 + mi * 16 + kg * 4;
      int col = ltile * 128 + wn * 64 + ni * 16 + m16;
#pragma unroll
      for (int r = 0; r < 4; ++r)
        __builtin_nontemporal_store(acc[mi][ni][r],
                                    &y[(size_t)(row0 + r) * L_FFT + col]);
    }
}

// ---------------------------------------------------------------------------
extern "C" void kernel_launch(void* const* d_in, const int* in_sizes, int n_in,
                              void* d_out, int out_size, void* d_ws, size_t ws_size,
                              hipStream_t stream) {
  const float* q   = (const float*)d_in[0];
  const float* wre = (const float*)d_in[4];
  const float* wim = (const float*)d_in[5];
  const int* index = (const int*)d_in[6];
  float* y = (float*)d_out;
  char* ws = (char*)d_ws;

  // byte layout:
  // T1fh 1MB | T1fl 1MB | T2fh 1MB | T2fl 1MB | Afh 2MB | Afl 2MB | g 4MB |
  // ctab 16KB | stab 16KB | part np*4MB (at 13MB)
  unsigned short* T1fh = (unsigned short*)(ws);
  unsigned short* T1fl = (unsigned short*)(ws + (1u << 20));
  unsigned short* T2fh = (unsigned short*)(ws + (2u << 20));
  unsigned short* T2fl = (unsigned short*)(ws + (3u << 20));
  unsigned short* Afh  = (unsigned short*)(ws + (4u << 20));
  unsigned short* Afl  = (unsigned short*)(ws + (6u << 20));
  float* g             = (float*)(ws + (8u << 20));
  float* ctab          = (float*)(ws + (12u << 20));
  float* stab          = (float*)(ws + (12u << 20) + 16384);
  float* part          = (float*)(ws + (13u << 20));

  int np = 1;
  while (np < 16) {
    size_t need = (13u << 20) + (size_t)(np * 2) * (4u << 20);
    if (need <= ws_size) np *= 2; else break;
  }
  if ((13u << 20) + (size_t)np * (4u << 20) > ws_size) { np = 1; part = g; }
  int kspan = L_FFT / np;

  k0a_phase<<<dim3(16), dim3(256), 0, stream>>>(ctab, stab);
  k0b_expand<<<dim3(2048), dim3(256), 0, stream>>>(index, ctab, stab,
                                                   T1fh, T1fl, T2fh, T2fl);
  k1_forward<<<dim3(128, np), dim3(256), 0, stream>>>(q, T1fh, T1fl, part, kspan);
  if (np > 1)
    k1b_reduce<<<dim3(4096), dim3(256), 0, stream>>>(part, g, np);
  k2_mix<<<dim3(16, 8, 16), dim3(256), 0, stream>>>(g, wre, wim, Afh, Afl);
  k3_inverse<<<dim3(32, 64), dim3(256), 0, stream>>>(Afh, Afl, T2fh, T2fl, y);
}

// Round 6
// 123.370 us; speedup vs baseline: 1.2313x; 1.2313x over previous
//
#include <hip/hip_runtime.h>

#define L_FFT 4096
#define NCH 512

typedef __attribute__((ext_vector_type(8))) short bf16x8;
typedef __attribute__((ext_vector_type(4))) float f32x4;

__device__ __forceinline__ void split_bf16(float x, unsigned short& h, unsigned short& l) {
  unsigned u = __float_as_uint(x);
  h = (unsigned short)(u >> 16);                    // truncate -> hi
  float fh = __uint_as_float(u & 0xffff0000u);
  float lo = x - fh;                                // exact residual
  l = (unsigned short)(__float_as_uint(lo) >> 16);  // truncate -> lo
}

// ---------------------------------------------------------------------------
// k0a: phase tables ctab/stab[4096] = cos/sin(2*pi*ph/4096)
// ---------------------------------------------------------------------------
__global__ __launch_bounds__(256) void k0a_phase(float* __restrict__ ctab,
                                                 float* __restrict__ stab) {
  int i = blockIdx.x * 256 + threadIdx.x;  // 0..4095
  float s, c;
  sincosf(6.2831853071795864769f / 4096.f * (float)i, &s, &c);
  ctab[i] = c;
  stab[i] = s;
}

// ---------------------------------------------------------------------------
// k0b: expand phase tables into MFMA-fragment-swizzled bf16 hi/lo tables.
// T1f (forward B): idx = ((chunk*2+wn)*4+ni)*512 + lane*8 + i
//   kcol = wn*64+ni*16+(lane&15), l = chunk*32+(lane>>4)*8+i
// T2f (inverse B): idx = (lt16*4+kc2)*512 + lane*8 + i
//   l = lt16*16+(lane&15), k = kc2*32+(lane>>4)*8+i
// ---------------------------------------------------------------------------
__global__ __launch_bounds__(256) void k0b_expand(const int* __restrict__ index,
                                                  const float* __restrict__ ctab,
                                                  const float* __restrict__ stab,
                                                  unsigned short* __restrict__ T1fh,
                                                  unsigned short* __restrict__ T1fl,
                                                  unsigned short* __restrict__ T2fh,
                                                  unsigned short* __restrict__ T2fl) {
  int idx = blockIdx.x * 256 + threadIdx.x;  // 0..524287
  int i = idx & 7, lane = (idx >> 3) & 63;
  int m16 = lane & 15, kg = lane >> 4;
  {
    int ni = (idx >> 9) & 3, wn = (idx >> 11) & 1, chunk = idx >> 12;
    int kcol = wn * 64 + ni * 16 + m16;
    int l = chunk * 32 + kg * 8 + i;
    int f = index[kcol & 63];
    int ph = (l * f) & 4095;
    float v = (kcol < 64) ? ctab[ph] : -stab[ph];
    unsigned short h, lo;
    split_bf16(v, h, lo);
    T1fh[idx] = h;
    T1fl[idx] = lo;
  }
  {
    int kc2 = (idx >> 9) & 3, lt16 = idx >> 11;
    int l = lt16 * 16 + m16;
    int k = kc2 * 32 + kg * 8 + i;
    int ph = (l * (k & 63)) & 4095;
    float v = (k < 64) ? ctab[ph] : stab[ph];
    unsigned short h, lo;
    split_bf16(v, h, lo);
    T2fh[idx] = h;
    T2fl[idx] = lo;
  }
}

// ---------------------------------------------------------------------------
// k1: forward GEMM, zero LDS, register double-buffered with STATIC indexing
// (named xfA/xfB buffers, 2x-unrolled chunk loop -> no scratch, rule #20).
// part[p][c][k] = sum_l X[c,l]*T1[k,l]
// Block 64c x 128k (4 waves; wave 32c x 64k as 2x4 of 16x16x32), chunk=32 l.
// ---------------------------------------------------------------------------
__global__ __launch_bounds__(256, 4) void k1_forward(const float* __restrict__ q,
                                                     const unsigned short* __restrict__ T1fh,
                                                     const unsigned short* __restrict__ T1fl,
                                                     float* __restrict__ part,
                                                     int kspan) {
  int ctile = blockIdx.x;  // 0..127
  int p = blockIdx.y;
  int b = ctile >> 3, ch0 = (ctile & 7) * 64;
  int t = threadIdx.x, wave = t >> 6, lane = t & 63;
  int wm = wave >> 1, wn = wave & 1, m16 = lane & 15, kg = lane >> 4;
  int nchunk = kspan >> 5;          // even for np in {1,2,4,8,16}
  int chunk0 = (p * kspan) >> 5;

  const float* qbase = q + (size_t)b * L_FFT * NCH + (size_t)kg * 8 * NCH
                         + (ch0 + wm * 32 + m16);

  float xfA[2][8], xfB[2][8];
  f32x4 acc[2][4] = {};

#define K1_GLOAD(BUF, CHUNK)                                                  \
  do {                                                                        \
    const float* qp_ = qbase + (size_t)(CHUNK) * 32 * NCH;                    \
    _Pragma("unroll") for (int mi_ = 0; mi_ < 2; ++mi_)                       \
      _Pragma("unroll") for (int i_ = 0; i_ < 8; ++i_)                        \
        BUF[mi_][i_] = qp_[i_ * NCH + mi_ * 16];                              \
  } while (0)

#define K1_COMPUTE(BUF, CHUNK)                                                \
  do {                                                                        \
    bf16x8 bh_[4], bl_[4];                                                    \
    _Pragma("unroll") for (int ni_ = 0; ni_ < 4; ++ni_) {                     \
      size_t off_ = ((size_t)(((CHUNK)*2 + wn) * 4 + ni_) << 9) + lane * 8;   \
      bh_[ni_] = *(const bf16x8*)(T1fh + off_);                               \
      bl_[ni_] = *(const bf16x8*)(T1fl + off_);                               \
    }                                                                         \
    _Pragma("unroll") for (int mi_ = 0; mi_ < 2; ++mi_) {                     \
      union { bf16x8 v; unsigned w[4]; } ah_, al_;                            \
      _Pragma("unroll") for (int j_ = 0; j_ < 4; ++j_) {                      \
        float x0_ = BUF[mi_][2 * j_], x1_ = BUF[mi_][2 * j_ + 1];             \
        unsigned u0_ = __float_as_uint(x0_), u1_ = __float_as_uint(x1_);      \
        ah_.w[j_] = (u0_ >> 16) | (u1_ & 0xffff0000u);                        \
        float l0_ = x0_ - __uint_as_float(u0_ & 0xffff0000u);                 \
        float l1_ = x1_ - __uint_as_float(u1_ & 0xffff0000u);                 \
        al_.w[j_] = (__float_as_uint(l0_) >> 16) |                            \
                    (__float_as_uint(l1_) & 0xffff0000u);                     \
      }                                                                       \
      _Pragma("unroll") for (int ni_ = 0; ni_ < 4; ++ni_) {                   \
        acc[mi_][ni_] = __builtin_amdgcn_mfma_f32_16x16x32_bf16(              \
            ah_.v, bh_[ni_], acc[mi_][ni_], 0, 0, 0);                         \
        acc[mi_][ni_] = __builtin_amdgcn_mfma_f32_16x16x32_bf16(              \
            ah_.v, bl_[ni_], acc[mi_][ni_], 0, 0, 0);                         \
        acc[mi_][ni_] = __builtin_amdgcn_mfma_f32_16x16x32_bf16(              \
            al_.v, bh_[ni_], acc[mi_][ni_], 0, 0, 0);                         \
      }                                                                       \
    }                                                                         \
  } while (0)

  K1_GLOAD(xfA, chunk0);
  for (int cc = 0; cc < nchunk; cc += 2) {
    K1_GLOAD(xfB, chunk0 + cc + 1);       // prefetch odd chunk (HBM latency)
    K1_COMPUTE(xfA, chunk0 + cc);         // compute even chunk
    if (cc + 2 < nchunk)
      K1_GLOAD(xfA, chunk0 + cc + 2);     // prefetch next even chunk
    K1_COMPUTE(xfB, chunk0 + cc + 1);     // compute odd chunk
  }
#undef K1_GLOAD
#undef K1_COMPUTE

  int base_c = ctile * 64 + wm * 32;
  float* dst = part + (size_t)p * 1048576;
#pragma unroll
  for (int mi = 0; mi < 2; ++mi)
#pragma unroll
    for (int ni = 0; ni < 4; ++ni) {
      int row0 = base_c + mi * 16 + kg * 4;
      int col = wn * 64 + ni * 16 + m16;
#pragma unroll
      for (int r = 0; r < 4; ++r)
        __builtin_nontemporal_store(acc[mi][ni][r],
                                    &dst[(size_t)(row0 + r) * 128 + col]);
    }
}

// k1b: reduce split-K partials -> g [8192][128] f32
__global__ __launch_bounds__(256) void k1b_reduce(const float* __restrict__ part,
                                                  float* __restrict__ g, int np) {
  int idx = blockIdx.x * 256 + threadIdx.x;
  float s = 0.f;
  for (int p = 0; p < np; ++p) s += part[(size_t)p * 1048576 + idx];
  g[idx] = s;
}

// ---------------------------------------------------------------------------
// k2: mode mix + irfft coefficient prep -> Afh/Afl bf16, k3-fragment-swizzled.
// (round-3 version: grid (16,8,16), g-slice in LDS, w streamed through L3)
// afidx(c,k) = (((c>>4)*4+(k>>5))*64 + ((k>>3)&3)*16 + (c&15))*8 + (k&7)
// ---------------------------------------------------------------------------
__global__ __launch_bounds__(256) void k2_mix(const float* __restrict__ g,
                                              const float* __restrict__ wre,
                                              const float* __restrict__ wim,
                                              unsigned short* __restrict__ Afh,
                                              unsigned short* __restrict__ Afl) {
  int oq = blockIdx.x;  // 16
  int h = blockIdx.y;   // 8
  int b = blockIdx.z;   // 16
  __shared__ float gre[64][64], gim[64][64];
  int t = threadIdx.x;
  int bh = b * 8 + h;
#pragma unroll
  for (int j = 0; j < 16; ++j) {
    int idx = j * 256 + t, ir = idx >> 6, mr = idx & 63;
    const float* row = &g[((size_t)bh * 64 + ir) * 128];
    gre[ir][mr] = row[mr];
    gim[ir][mr] = row[64 + mr];
  }
  __syncthreads();
  int o = oq * 4 + (t >> 6), m = t & 63;
  float are = 0.f, aim = 0.f;
  for (int i = 0; i < 64; ++i) {
    float gr = gre[i][m], gi = gim[i][m];
    int wofs = ((h * 64 + i) * 64 + o) * 64 + m;
    float wr = wre[wofs], wi = wim[wofs];
    are = fmaf(gr, wr, are);
    are = fmaf(-gi, wi, are);
    aim = fmaf(gr, wi, aim);
    aim = fmaf(gi, wr, aim);
  }
  const float invL = 1.0f / (float)L_FFT;
  float outre = are * ((m == 0) ? invL : 2.0f * invL);
  float outim = (m == 0) ? 0.0f : (-2.0f * invL) * aim;
  int c = bh * 64 + o;
  unsigned short h16, l16;
  {
    int k = m;
    int afidx = (((c >> 4) * 4 + (k >> 5)) * 64 + ((k >> 3) & 3) * 16 + (c & 15)) * 8 + (k & 7);
    split_bf16(outre, h16, l16);
    Afh[afidx] = h16;
    Afl[afidx] = l16;
  }
  {
    int k = 64 + m;
    int afidx = (((c >> 4) * 4 + (k >> 5)) * 64 + ((k >> 3) & 3) * 16 + (c & 15)) * 8 + (k & 7);
    split_bf16(outim, h16, l16);
    Afh[afidx] = h16;
    Afl[afidx] = l16;
  }
}

// ---------------------------------------------------------------------------
// k3: inverse GEMM, zero LDS, all operands fragment-swizzled & coalesced.
// y[c][l] = sum_k A[c][k] * T2[l][k]; block 128c x 128l, K=128 in 4 chunks.
// ---------------------------------------------------------------------------
__global__ __launch_bounds__(256) void k3_inverse(const unsigned short* __restrict__ Afh,
                                                  const unsigned short* __restrict__ Afl,
                                                  const unsigned short* __restrict__ T2fh,
                                                  const unsigned short* __restrict__ T2fl,
                                                  float* __restrict__ y) {
  int ltile = blockIdx.x;   // 0..31
  int c0 = blockIdx.y * 128;
  int t = threadIdx.x, wave = t >> 6, lane = t & 63;
  int wm = wave >> 1, wn = wave & 1, m16 = lane & 15, kg = lane >> 4;

  f32x4 acc[4][4] = {};

#pragma unroll
  for (int kc2 = 0; kc2 < 4; ++kc2) {
    bf16x8 bh[4], bl[4];
#pragma unroll
    for (int ni = 0; ni < 4; ++ni) {
      size_t off = ((size_t)((ltile * 8 + wn * 4 + ni) * 4 + kc2) << 9) + lane * 8;
      bh[ni] = *(const bf16x8*)(T2fh + off);
      bl[ni] = *(const bf16x8*)(T2fl + off);
    }
#pragma unroll
    for (int mi = 0; mi < 4; ++mi) {
      int c16 = (c0 >> 4) + wm * 4 + mi;
      size_t off = ((size_t)(c16 * 4 + kc2) << 9) + lane * 8;
      bf16x8 ah = *(const bf16x8*)(Afh + off);
      bf16x8 al = *(const bf16x8*)(Afl + off);
#pragma unroll
      for (int ni = 0; ni < 4; ++ni) {
        acc[mi][ni] = __builtin_amdgcn_mfma_f32_16x16x32_bf16(ah, bh[ni], acc[mi][ni], 0, 0, 0);
        acc[mi][ni] = __builtin_amdgcn_mfma_f32_16x16x32_bf16(ah, bl[ni], acc[mi][ni], 0, 0, 0);
        acc[mi][ni] = __builtin_amdgcn_mfma_f32_16x16x32_bf16(al, bh[ni], acc[mi][ni], 0, 0, 0);
      }
    }
  }

#pragma unroll
  for (int mi = 0; mi < 4; ++mi)
#pragma unroll
    for (int ni = 0; ni < 4; ++ni) {
      int row0 = c0 + wm * 64 + mi * 16 + kg * 4;
      int col = ltile * 128 + wn * 64 + ni * 16 + m16;
#pragma unroll
      for (int r = 0; r < 4; ++r)
        __builtin_nontemporal_store(acc[mi][ni][r],
                                    &y[(size_t)(row0 + r) * L_FFT + col]);
    }
}

// ---------------------------------------------------------------------------
extern "C" void kernel_launch(void* const* d_in, const int* in_sizes, int n_in,
                              void* d_out, int out_size, void* d_ws, size_t ws_size,
                              hipStream_t stream) {
  const float* q   = (const float*)d_in[0];
  const float* wre = (const float*)d_in[4];
  const float* wim = (const float*)d_in[5];
  const int* index = (const int*)d_in[6];
  float* y = (float*)d_out;
  char* ws = (char*)d_ws;

  // byte layout:
  // T1fh 1MB | T1fl 1MB | T2fh 1MB | T2fl 1MB | Afh 2MB | Afl 2MB | g 4MB |
  // ctab 16KB | stab 16KB | part np*4MB (at 13MB)
  unsigned short* T1fh = (unsigned short*)(ws);
  unsigned short* T1fl = (unsigned short*)(ws + (1u << 20));
  unsigned short* T2fh = (unsigned short*)(ws + (2u << 20));
  unsigned short* T2fl = (unsigned short*)(ws + (3u << 20));
  unsigned short* Afh  = (unsigned short*)(ws + (4u << 20));
  unsigned short* Afl  = (unsigned short*)(ws + (6u << 20));
  float* g             = (float*)(ws + (8u << 20));
  float* ctab          = (float*)(ws + (12u << 20));
  float* stab          = (float*)(ws + (12u << 20) + 16384);
  float* part          = (float*)(ws + (13u << 20));

  int np = 1;
  while (np < 8) {
    size_t need = (13u << 20) + (size_t)(np * 2) * (4u << 20);
    if (need <= ws_size) np *= 2; else break;
  }
  if ((13u << 20) + (size_t)np * (4u << 20) > ws_size) { np = 1; part = g; }
  int kspan = L_FFT / np;

  k0a_phase<<<dim3(16), dim3(256), 0, stream>>>(ctab, stab);
  k0b_expand<<<dim3(2048), dim3(256), 0, stream>>>(index, ctab, stab,
                                                   T1fh, T1fl, T2fh, T2fl);
  k1_forward<<<dim3(128, np), dim3(256), 0, stream>>>(q, T1fh, T1fl, part, kspan);
  if (np > 1)
    k1b_reduce<<<dim3(4096), dim3(256), 0, stream>>>(part, g, np);
  k2_mix<<<dim3(16, 8, 16), dim3(256), 0, stream>>>(g, wre, wim, Afh, Afl);
  k3_inverse<<<dim3(32, 64), dim3(256), 0, stream>>>(Afh, Afl, T2fh, T2fl, y);
}